// Round 1
// baseline (404.900 us; speedup 1.0000x reference)
//
#include <hip/hip_runtime.h>
#include <math.h>

#define B_TOT 262144

typedef __attribute__((ext_vector_type(8))) short v8s;
typedef __attribute__((ext_vector_type(4))) float v4f;

// ws layout (bf16 element offsets):
//  W1 frag-order   [0, 20480)        (8 n-tiles x 5 k-chunks x 512)
//  W2 frag-order   [20480, 36864)    (8 x 4 x 512)
//  Wf frag-order   [36864, 53248)    (8 x 4 x 512)
//  seen frag-order [53248, 67584)    (7 x 4 x 512, rows >=100 zero-padded)
//  s2 (fp32)       byte offset 135168, 112 floats (1e30 for pad rows)
#define WS_W1 0
#define WS_W2 20480
#define WS_WF 36864
#define WS_SEEN 53248
#define WS_S2_BYTES 135168

__device__ __forceinline__ unsigned short f2bf(float f) {
  union { float f; unsigned u; } cv; cv.f = f;
  unsigned u = cv.u;
  return (unsigned short)((u + 0x7FFFu + ((u >> 16) & 1u)) >> 16);  // RNE
}
__device__ __forceinline__ float bf2f(unsigned short h) {
  union { unsigned u; float f; } cv; cv.u = ((unsigned)h) << 16;
  return cv.f;
}
__device__ __forceinline__ v8s cvt8(const float* __restrict__ p) {
  float4 f0 = *(const float4*)p;
  float4 f1 = *(const float4*)(p + 4);
  v8s a;
  a[0] = (short)f2bf(f0.x); a[1] = (short)f2bf(f0.y);
  a[2] = (short)f2bf(f0.z); a[3] = (short)f2bf(f0.w);
  a[4] = (short)f2bf(f1.x); a[5] = (short)f2bf(f1.y);
  a[6] = (short)f2bf(f1.z); a[7] = (short)f2bf(f1.w);
  return a;
}

// Repack weights to bf16 in MFMA B-fragment-linear order.
// B-frag for (tile t, k-chunk c): lane L holds B[n = t*16 + (L&15)][k = c*32 + (L>>4)*8 + j]
__global__ void curiosity_prep(const float* __restrict__ W1, const float* __restrict__ W2,
                               const float* __restrict__ Wf, const float* __restrict__ seen,
                               unsigned short* __restrict__ wsb, float* __restrict__ s2) {
  int idx = blockIdx.x * 256 + threadIdx.x;
  if (idx < 20480) {                       // W1: [128][160]
    int f = idx >> 9, r = idx & 511, L = r >> 3, j = r & 7;
    int t = f / 5, c = f - t * 5;
    int n = t * 16 + (L & 15), k = c * 32 + (L >> 4) * 8 + j;
    wsb[idx] = f2bf(W1[n * 160 + k]);
  } else if (idx < 36864) {                // W2: [128][128]
    int e = idx - 20480;
    int f = e >> 9, r = e & 511, L = r >> 3, j = r & 7;
    int t = f >> 2, c = f & 3;
    int n = t * 16 + (L & 15), k = c * 32 + (L >> 4) * 8 + j;
    wsb[idx] = f2bf(W2[n * 128 + k]);
  } else if (idx < 53248) {                // Wf: [128][128]
    int e = idx - 36864;
    int f = e >> 9, r = e & 511, L = r >> 3, j = r & 7;
    int t = f >> 2, c = f & 3;
    int n = t * 16 + (L & 15), k = c * 32 + (L >> 4) * 8 + j;
    wsb[idx] = f2bf(Wf[n * 128 + k]);
  } else if (idx < 67584) {                // seen: [100->112][128]
    int e = idx - 53248;
    int f = e >> 9, r = e & 511, L = r >> 3, j = r & 7;
    int t = f >> 2, c = f & 3;
    int n = t * 16 + (L & 15), k = c * 32 + (L >> 4) * 8 + j;
    float v = (n < 100) ? seen[n * 128 + k] : 0.f;
    wsb[idx] = f2bf(v);
  } else if (idx < 67696) {                // s2
    int mm = idx - 67584;
    float s = 1e30f;
    if (mm < 100) {
      s = 0.f;
      for (int k = 0; k < 128; ++k) { float v = seen[mm * 128 + k]; s += v * v; }
    }
    s2[mm] = s;
  }
}

__device__ __forceinline__ void stage(const unsigned short* __restrict__ src,
                                      unsigned short* dst, int nelem, int tid) {
  const uint4* s = (const uint4*)src;
  uint4* d = (uint4*)dst;
  int n = nelem >> 3;
  for (int i = tid; i < n; i += 256) d[i] = s[i];
}

// 4096 blocks x 256 threads; 4 waves/block, 16 batch rows per wave.
// LDS: 20480B weight slice + 4x2x4352B wave-private intermediates + 768B out = 56 KB -> 2 blocks/CU
__global__ __launch_bounds__(256, 2) void curiosity_main(
    const float* __restrict__ state, const float* __restrict__ action,
    const float* __restrict__ next_state,
    const float* __restrict__ b1, const float* __restrict__ b2,
    const float* __restrict__ bfv,
    const unsigned short* __restrict__ wsb, const float* __restrict__ s2g,
    float* __restrict__ out) {
  __shared__ __attribute__((aligned(16))) unsigned short s_w[10240];
  __shared__ __attribute__((aligned(16))) unsigned short s_int[4][2][2176]; // [wave][buf][16*136]
  __shared__ float s_o[192];

  const int tid = (int)threadIdx.x;
  const int w = tid >> 6, lane = tid & 63;
  const int m = lane & 15, q = lane >> 4;
  const int row0 = (int)blockIdx.x * 64 + w * 16;
  const int gr = row0 + m;

  unsigned short* hbuf = &s_int[w][0][0];  // h, later fa
  unsigned short* pbuf = &s_int[w][1][0];  // pn

  // ---- A-fragments for GEMM1 (x = [state|action]), K=160 -> 5 chunks
  v8s a1[5];
  {
    const float* sr = state + (size_t)gr * 128;
#pragma unroll
    for (int c = 0; c < 4; ++c) a1[c] = cvt8(sr + c * 32 + q * 8);
    a1[4] = cvt8(action + (size_t)gr * 32 + q * 8);
  }

  // ---- GEMM1: h = relu(x @ W1^T + b1), N=128 in two halves of 64
#pragma unroll
  for (int hf = 0; hf < 2; ++hf) {
    __syncthreads();
    stage(wsb + WS_W1 + hf * 10240, s_w, 10240, tid);
    __syncthreads();
    v4f acc[4] = {{0.f,0.f,0.f,0.f},{0.f,0.f,0.f,0.f},{0.f,0.f,0.f,0.f},{0.f,0.f,0.f,0.f}};
#pragma unroll
    for (int c = 0; c < 5; ++c) {
#pragma unroll
      for (int tl = 0; tl < 4; ++tl) {
        v8s b = *(const v8s*)(s_w + (tl * 5 + c) * 512 + lane * 8);
        acc[tl] = __builtin_amdgcn_mfma_f32_16x16x32_bf16(a1[c], b, acc[tl], 0, 0, 0);
      }
    }
#pragma unroll
    for (int tl = 0; tl < 4; ++tl) {
      int tg = hf * 4 + tl;
      float bv = b1[tg * 16 + m];
#pragma unroll
      for (int r = 0; r < 4; ++r) {
        float hv = acc[tl][r] + bv;
        hv = hv > 0.f ? hv : 0.f;
        hbuf[(q * 4 + r) * 136 + tg * 16 + m] = f2bf(hv);
      }
    }
  }

  // ---- GEMM2: pn = h @ W2^T + b2
  v8s af[4];
#pragma unroll
  for (int c = 0; c < 4; ++c)
    af[c] = *(const v8s*)(hbuf + m * 136 + c * 32 + q * 8);
#pragma unroll
  for (int hf = 0; hf < 2; ++hf) {
    __syncthreads();
    stage(wsb + WS_W2 + hf * 8192, s_w, 8192, tid);
    __syncthreads();
    v4f acc[4] = {{0.f,0.f,0.f,0.f},{0.f,0.f,0.f,0.f},{0.f,0.f,0.f,0.f},{0.f,0.f,0.f,0.f}};
#pragma unroll
    for (int c = 0; c < 4; ++c) {
#pragma unroll
      for (int tl = 0; tl < 4; ++tl) {
        v8s b = *(const v8s*)(s_w + (tl * 4 + c) * 512 + lane * 8);
        acc[tl] = __builtin_amdgcn_mfma_f32_16x16x32_bf16(af[c], b, acc[tl], 0, 0, 0);
      }
    }
#pragma unroll
    for (int tl = 0; tl < 4; ++tl) {
      int tg = hf * 4 + tl;
      float bv = b2[tg * 16 + m];
#pragma unroll
      for (int r = 0; r < 4; ++r)
        pbuf[(q * 4 + r) * 136 + tg * 16 + m] = f2bf(acc[tl][r] + bv);
    }
  }

  // ---- GEMM3+4 (share Wf): fa = relu(ns@Wf^T+bf), fp = relu(pn@Wf^T+bf)
  v8s a3[4], a4[4];
  {
    const float* nr = next_state + (size_t)gr * 128;
#pragma unroll
    for (int c = 0; c < 4; ++c) a3[c] = cvt8(nr + c * 32 + q * 8);
#pragma unroll
    for (int c = 0; c < 4; ++c)
      a4[c] = *(const v8s*)(pbuf + m * 136 + c * 32 + q * 8);
  }
  float pe[4] = {0.f, 0.f, 0.f, 0.f}, a2s[4] = {0.f, 0.f, 0.f, 0.f};
#pragma unroll
  for (int hf = 0; hf < 2; ++hf) {
    __syncthreads();
    stage(wsb + WS_WF + hf * 8192, s_w, 8192, tid);
    __syncthreads();
    v4f accA[4] = {{0.f,0.f,0.f,0.f},{0.f,0.f,0.f,0.f},{0.f,0.f,0.f,0.f},{0.f,0.f,0.f,0.f}};
    v4f accP[4] = {{0.f,0.f,0.f,0.f},{0.f,0.f,0.f,0.f},{0.f,0.f,0.f,0.f},{0.f,0.f,0.f,0.f}};
#pragma unroll
    for (int c = 0; c < 4; ++c) {
#pragma unroll
      for (int tl = 0; tl < 4; ++tl) {
        v8s b = *(const v8s*)(s_w + (tl * 4 + c) * 512 + lane * 8);
        accA[tl] = __builtin_amdgcn_mfma_f32_16x16x32_bf16(a3[c], b, accA[tl], 0, 0, 0);
        accP[tl] = __builtin_amdgcn_mfma_f32_16x16x32_bf16(a4[c], b, accP[tl], 0, 0, 0);
      }
    }
#pragma unroll
    for (int tl = 0; tl < 4; ++tl) {
      int tg = hf * 4 + tl;
      float bv = bfv[tg * 16 + m];
#pragma unroll
      for (int r = 0; r < 4; ++r) {
        float fav = accA[tl][r] + bv; fav = fav > 0.f ? fav : 0.f;
        unsigned short fb = f2bf(fav);
        float fbr = bf2f(fb);
        hbuf[(q * 4 + r) * 136 + tg * 16 + m] = fb;  // fa (bf16) for GEMM5
        float fpv = accP[tl][r] + bv; fpv = fpv > 0.f ? fpv : 0.f;
        float d = fpv - fav;
        pe[r] += d * d;
        a2s[r] += fbr * fbr;
      }
    }
  }
  // reduce pe / ||fa||^2 across the 16 lanes of each quad (C-frag col dim)
#pragma unroll
  for (int r = 0; r < 4; ++r) {
#pragma unroll
    for (int mask = 1; mask < 16; mask <<= 1) {
      pe[r] += __shfl_xor(pe[r], mask, 16);
      a2s[r] += __shfl_xor(a2s[r], mask, 16);
    }
  }

  // ---- GEMM5: g = fa @ seen^T (N=112), d2 = a2 + s2 - 2g
  v8s a5[4];
#pragma unroll
  for (int c = 0; c < 4; ++c)
    a5[c] = *(const v8s*)(hbuf + m * 136 + c * 32 + q * 8);
  float dmin[4] = {3.4e38f, 3.4e38f, 3.4e38f, 3.4e38f};

  __syncthreads();
  stage(wsb + WS_SEEN, s_w, 8192, tid);
  __syncthreads();
  {
    v4f g[4] = {{0.f,0.f,0.f,0.f},{0.f,0.f,0.f,0.f},{0.f,0.f,0.f,0.f},{0.f,0.f,0.f,0.f}};
#pragma unroll
    for (int c = 0; c < 4; ++c) {
#pragma unroll
      for (int tl = 0; tl < 4; ++tl) {
        v8s b = *(const v8s*)(s_w + (tl * 4 + c) * 512 + lane * 8);
        g[tl] = __builtin_amdgcn_mfma_f32_16x16x32_bf16(a5[c], b, g[tl], 0, 0, 0);
      }
    }
#pragma unroll
    for (int tl = 0; tl < 4; ++tl) {
      float s2v = s2g[tl * 16 + m];
#pragma unroll
      for (int r = 0; r < 4; ++r) {
        float d2 = a2s[r] + s2v - 2.f * g[tl][r];
        dmin[r] = fminf(dmin[r], d2);
      }
    }
  }
  __syncthreads();
  stage(wsb + WS_SEEN + 8192, s_w, 6144, tid);
  __syncthreads();
  {
    v4f g[3] = {{0.f,0.f,0.f,0.f},{0.f,0.f,0.f,0.f},{0.f,0.f,0.f,0.f}};
#pragma unroll
    for (int c = 0; c < 4; ++c) {
#pragma unroll
      for (int tl = 0; tl < 3; ++tl) {
        v8s b = *(const v8s*)(s_w + (tl * 4 + c) * 512 + lane * 8);
        g[tl] = __builtin_amdgcn_mfma_f32_16x16x32_bf16(a5[c], b, g[tl], 0, 0, 0);
      }
    }
#pragma unroll
    for (int tl = 0; tl < 3; ++tl) {
      float s2v = s2g[(4 + tl) * 16 + m];
#pragma unroll
      for (int r = 0; r < 4; ++r) {
        float d2 = a2s[r] + s2v - 2.f * g[tl][r];
        dmin[r] = fminf(dmin[r], d2);
      }
    }
  }
#pragma unroll
  for (int r = 0; r < 4; ++r) {
#pragma unroll
    for (int mask = 1; mask < 16; mask <<= 1)
      dmin[r] = fminf(dmin[r], __shfl_xor(dmin[r], mask, 16));
  }

  if (m == 0) {
#pragma unroll
    for (int r = 0; r < 4; ++r) {
      int rr = w * 16 + q * 4 + r;
      float p = pe[r] * (1.f / 128.f);
      float nov = fminf(1.f, sqrtf(fmaxf(dmin[r], 0.f)) * 0.1f);
      s_o[rr * 3 + 0] = p;
      s_o[rr * 3 + 1] = nov;
      s_o[rr * 3 + 2] = 0.5f * (p + nov);
    }
  }
  __syncthreads();
  if (tid < 192) {
    int j = tid >> 6, r = tid & 63;
    out[(size_t)j * B_TOT + (size_t)blockIdx.x * 64 + r] = s_o[r * 3 + j];
  }
}

extern "C" void kernel_launch(void* const* d_in, const int* in_sizes, int n_in,
                              void* d_out, int out_size, void* d_ws, size_t ws_size,
                              hipStream_t stream) {
  const float* state      = (const float*)d_in[0];
  const float* action     = (const float*)d_in[1];
  const float* next_state = (const float*)d_in[2];
  const float* seen       = (const float*)d_in[3];
  const float* W1         = (const float*)d_in[4];
  const float* b1         = (const float*)d_in[5];
  const float* W2         = (const float*)d_in[6];
  const float* b2         = (const float*)d_in[7];
  const float* Wf         = (const float*)d_in[8];
  const float* bf_        = (const float*)d_in[9];

  unsigned short* wsb = (unsigned short*)d_ws;
  float* s2 = (float*)((char*)d_ws + WS_S2_BYTES);

  curiosity_prep<<<265, 256, 0, stream>>>(W1, W2, Wf, seen, wsb, s2);
  curiosity_main<<<4096, 256, 0, stream>>>(state, action, next_state, b1, b2, bf_,
                                           wsb, s2, (float*)d_out);
}

// Round 2
// 385.397 us; speedup vs baseline: 1.0506x; 1.0506x over previous
//
#include <hip/hip_runtime.h>
#include <math.h>

#define B_TOT 262144

typedef __attribute__((ext_vector_type(8))) short v8s;
typedef __attribute__((ext_vector_type(4))) float v4f;

// ws layout (bf16 element offsets):
//  W1 frag-order   [0, 20480)        (8 n-tiles x 5 k-chunks x 512)
//  W2 frag-order   [20480, 36864)    (8 x 4 x 512)
//  Wf frag-order   [36864, 53248)    (8 x 4 x 512)
//  seen frag-order [53248, 67584)    (7 x 4 x 512, rows >=100 zero-padded)
//  s2 (fp32)       byte offset 135168, 112 floats (1e30 for pad rows)
#define WS_W1 0
#define WS_W2 20480
#define WS_WF 36864
#define WS_SEEN 53248
#define WS_S2_BYTES 135168

__device__ __forceinline__ unsigned short f2bf(float f) {
  union { float f; unsigned u; } cv; cv.f = f;
  unsigned u = cv.u;
  return (unsigned short)((u + 0x7FFFu + ((u >> 16) & 1u)) >> 16);  // RNE
}
__device__ __forceinline__ float bf2f(unsigned short h) {
  union { unsigned u; float f; } cv; cv.u = ((unsigned)h) << 16;
  return cv.f;
}

// Repack weights to bf16 in MFMA B-fragment-linear order.
// B-frag for (tile t, k-chunk c): lane L holds B[n = t*16 + (L&15)][k = c*32 + (L>>4)*8 + j]
__global__ void curiosity_prep(const float* __restrict__ W1, const float* __restrict__ W2,
                               const float* __restrict__ Wf, const float* __restrict__ seen,
                               unsigned short* __restrict__ wsb, float* __restrict__ s2) {
  int bid = blockIdx.x;
  if (bid < 264) {
    int idx = bid * 256 + (int)threadIdx.x;  // < 67584
    if (idx < 20480) {                       // W1: [128][160]
      int f = idx >> 9, r = idx & 511, L = r >> 3, j = r & 7;
      int t = f / 5, c = f - t * 5;
      int n = t * 16 + (L & 15), k = c * 32 + (L >> 4) * 8 + j;
      wsb[idx] = f2bf(W1[n * 160 + k]);
    } else if (idx < 36864) {                // W2: [128][128]
      int e = idx - 20480;
      int f = e >> 9, r = e & 511, L = r >> 3, j = r & 7;
      int t = f >> 2, c = f & 3;
      int n = t * 16 + (L & 15), k = c * 32 + (L >> 4) * 8 + j;
      wsb[idx] = f2bf(W2[n * 128 + k]);
    } else if (idx < 53248) {                // Wf: [128][128]
      int e = idx - 36864;
      int f = e >> 9, r = e & 511, L = r >> 3, j = r & 7;
      int t = f >> 2, c = f & 3;
      int n = t * 16 + (L & 15), k = c * 32 + (L >> 4) * 8 + j;
      wsb[idx] = f2bf(Wf[n * 128 + k]);
    } else {                                 // seen: [100->112][128]
      int e = idx - 53248;
      int f = e >> 9, r = e & 511, L = r >> 3, j = r & 7;
      int t = f >> 2, c = f & 3;
      int n = t * 16 + (L & 15), k = c * 32 + (L >> 4) * 8 + j;
      float v = (n < 100) ? seen[n * 128 + k] : 0.f;
      wsb[idx] = f2bf(v);
    }
  } else {                                   // s2: one wave per row
    int wv = (int)threadIdx.x >> 6, lane = (int)threadIdx.x & 63;
    int mm = (bid - 264) * 4 + wv;           // 0..111
    float s;
    if (mm < 100) {
      float v0 = seen[mm * 128 + lane], v1 = seen[mm * 128 + 64 + lane];
      s = v0 * v0 + v1 * v1;
#pragma unroll
      for (int msk = 1; msk < 64; msk <<= 1) s += __shfl_xor(s, msk, 64);
    } else {
      s = 1e30f;
    }
    if (lane == 0) s2[mm] = s;
  }
}

// stage a [16 x 128] f32 tile (row stride 128 floats) into wave-private LDS as bf16, stride 136
__device__ __forceinline__ void stage16x128(const float* __restrict__ src,
                                            unsigned short* buf, int lane) {
#pragma unroll
  for (int i = 0; i < 8; ++i) {
    int flat = i * 64 + lane;                 // float4 index 0..511
    int row = flat >> 5, c4 = flat & 31;
    float4 v = *(const float4*)(src + row * 128 + c4 * 4);
    uint2 p;
    p.x = (unsigned)f2bf(v.x) | ((unsigned)f2bf(v.y) << 16);
    p.y = (unsigned)f2bf(v.z) | ((unsigned)f2bf(v.w) << 16);
    *(uint2*)(buf + row * 136 + c4 * 4) = p;
  }
}
// stage a [16 x 32] f32 tile into cols 0..31 of the buffer
__device__ __forceinline__ void stage16x32(const float* __restrict__ src,
                                           unsigned short* buf, int lane) {
#pragma unroll
  for (int i = 0; i < 2; ++i) {
    int flat = i * 64 + lane;                 // float4 index 0..127
    int row = flat >> 3, c4 = flat & 7;
    float4 v = *(const float4*)(src + row * 32 + c4 * 4);
    uint2 p;
    p.x = (unsigned)f2bf(v.x) | ((unsigned)f2bf(v.y) << 16);
    p.y = (unsigned)f2bf(v.z) | ((unsigned)f2bf(v.w) << 16);
    *(uint2*)(buf + row * 136 + c4 * 4) = p;
  }
}
__device__ __forceinline__ v8s read_frag(const unsigned short* buf, int m, int q, int c) {
  return *(const v8s*)(buf + m * 136 + c * 32 + q * 8);
}
__device__ __forceinline__ v8s wfrag(const unsigned short* __restrict__ wsb,
                                     int base, int fragIdx, int lane) {
  return *(const v8s*)(wsb + base + fragIdx * 512 + lane * 8);
}

// 2048 blocks x 256 threads; 4 waves/block; each wave owns 32 rows (2 MFMA row-tiles
// sharing every B-fragment). B-frags stream straight from L2 (no weight LDS, no
// mid-kernel barriers). LDS = 4 waves x 2 x 4.25KB + 1.5KB out = 36.4KB -> 4 blocks/CU.
__global__ __launch_bounds__(256, 4) void curiosity_main(
    const float* __restrict__ state, const float* __restrict__ action,
    const float* __restrict__ next_state,
    const float* __restrict__ b1, const float* __restrict__ b2,
    const float* __restrict__ bfv,
    const unsigned short* __restrict__ wsb, const float* __restrict__ s2g,
    float* __restrict__ out) {
  __shared__ __attribute__((aligned(16))) unsigned short s_int[4][2][2176];
  __shared__ float s_o[3][128];

  const int tid = (int)threadIdx.x;
  const int w = tid >> 6, lane = tid & 63;
  const int m = lane & 15, q = lane >> 4;
  const int rowblk = (int)blockIdx.x * 128 + w * 32;

  unsigned short* buf[2] = { &s_int[w][0][0], &s_int[w][1][0] };

  // ---- inputs for GEMM1: action (k=128..160) then state (k=0..128)
  v8s a1[2][5];
#pragma unroll
  for (int tt = 0; tt < 2; ++tt) {
    const int gr0 = rowblk + tt * 16;
    stage16x32(action + (size_t)gr0 * 32, buf[tt], lane);
    a1[tt][4] = *(const v8s*)(buf[tt] + m * 136 + q * 8);
    stage16x128(state + (size_t)gr0 * 128, buf[tt], lane);
#pragma unroll
    for (int c = 0; c < 4; ++c) a1[tt][c] = read_frag(buf[tt], m, q, c);
  }

  // ---- GEMM1: h = relu(x @ W1^T + b1)
#pragma unroll
  for (int hf = 0; hf < 2; ++hf) {
    v4f acc[2][4] = {};
#pragma unroll
    for (int c = 0; c < 5; ++c) {
#pragma unroll
      for (int tl = 0; tl < 4; ++tl) {
        v8s b = wfrag(wsb, WS_W1, (hf * 4 + tl) * 5 + c, lane);
        acc[0][tl] = __builtin_amdgcn_mfma_f32_16x16x32_bf16(a1[0][c], b, acc[0][tl], 0, 0, 0);
        acc[1][tl] = __builtin_amdgcn_mfma_f32_16x16x32_bf16(a1[1][c], b, acc[1][tl], 0, 0, 0);
      }
    }
#pragma unroll
    for (int tl = 0; tl < 4; ++tl) {
      int tg = hf * 4 + tl;
      float bv = b1[tg * 16 + m];
#pragma unroll
      for (int r = 0; r < 4; ++r) {
        float h0 = fmaxf(acc[0][tl][r] + bv, 0.f);
        float h1 = fmaxf(acc[1][tl][r] + bv, 0.f);
        buf[0][(q * 4 + r) * 136 + tg * 16 + m] = f2bf(h0);
        buf[1][(q * 4 + r) * 136 + tg * 16 + m] = f2bf(h1);
      }
    }
  }

  // ---- GEMM2: pn = h @ W2^T + b2
  v8s af[2][4];
#pragma unroll
  for (int tt = 0; tt < 2; ++tt)
#pragma unroll
    for (int c = 0; c < 4; ++c) af[tt][c] = read_frag(buf[tt], m, q, c);
#pragma unroll
  for (int hf = 0; hf < 2; ++hf) {
    v4f acc[2][4] = {};
#pragma unroll
    for (int c = 0; c < 4; ++c) {
#pragma unroll
      for (int tl = 0; tl < 4; ++tl) {
        v8s b = wfrag(wsb, WS_W2, (hf * 4 + tl) * 4 + c, lane);
        acc[0][tl] = __builtin_amdgcn_mfma_f32_16x16x32_bf16(af[0][c], b, acc[0][tl], 0, 0, 0);
        acc[1][tl] = __builtin_amdgcn_mfma_f32_16x16x32_bf16(af[1][c], b, acc[1][tl], 0, 0, 0);
      }
    }
#pragma unroll
    for (int tl = 0; tl < 4; ++tl) {
      int tg = hf * 4 + tl;
      float bv = b2[tg * 16 + m];
#pragma unroll
      for (int r = 0; r < 4; ++r) {
        buf[0][(q * 4 + r) * 136 + tg * 16 + m] = f2bf(acc[0][tl][r] + bv);
        buf[1][(q * 4 + r) * 136 + tg * 16 + m] = f2bf(acc[1][tl][r] + bv);
      }
    }
  }

  // ---- read pn as A-frags, then stage next_state (pn buffer reused)
  v8s a4[2][4], a3[2][4];
#pragma unroll
  for (int tt = 0; tt < 2; ++tt)
#pragma unroll
    for (int c = 0; c < 4; ++c) a4[tt][c] = read_frag(buf[tt], m, q, c);
#pragma unroll
  for (int tt = 0; tt < 2; ++tt) {
    const int gr0 = rowblk + tt * 16;
    stage16x128(next_state + (size_t)gr0 * 128, buf[tt], lane);
#pragma unroll
    for (int c = 0; c < 4; ++c) a3[tt][c] = read_frag(buf[tt], m, q, c);
  }

  // ---- GEMM3: fa = relu(ns @ Wf^T + bf)  (write fa to buf, accumulate ||fa||^2)
  float a2s[2][4] = {};
#pragma unroll
  for (int hf = 0; hf < 2; ++hf) {
    v4f acc[2][4] = {};
#pragma unroll
    for (int c = 0; c < 4; ++c) {
#pragma unroll
      for (int tl = 0; tl < 4; ++tl) {
        v8s b = wfrag(wsb, WS_WF, (hf * 4 + tl) * 4 + c, lane);
        acc[0][tl] = __builtin_amdgcn_mfma_f32_16x16x32_bf16(a3[0][c], b, acc[0][tl], 0, 0, 0);
        acc[1][tl] = __builtin_amdgcn_mfma_f32_16x16x32_bf16(a3[1][c], b, acc[1][tl], 0, 0, 0);
      }
    }
#pragma unroll
    for (int tl = 0; tl < 4; ++tl) {
      int tg = hf * 4 + tl;
      float bv = bfv[tg * 16 + m];
#pragma unroll
      for (int tt = 0; tt < 2; ++tt) {
#pragma unroll
        for (int r = 0; r < 4; ++r) {
          float fav = fmaxf(acc[tt][tl][r] + bv, 0.f);
          unsigned short fb = f2bf(fav);
          float fbr = bf2f(fb);
          buf[tt][(q * 4 + r) * 136 + tg * 16 + m] = fb;
          a2s[tt][r] += fbr * fbr;
        }
      }
    }
  }

  // ---- GEMM4: fp = relu(pn @ Wf^T + bf); pe += (fp - fa)^2 (fa re-read from LDS)
  float pe[2][4] = {};
#pragma unroll
  for (int hf = 0; hf < 2; ++hf) {
    v4f acc[2][4] = {};
#pragma unroll
    for (int c = 0; c < 4; ++c) {
#pragma unroll
      for (int tl = 0; tl < 4; ++tl) {
        v8s b = wfrag(wsb, WS_WF, (hf * 4 + tl) * 4 + c, lane);
        acc[0][tl] = __builtin_amdgcn_mfma_f32_16x16x32_bf16(a4[0][c], b, acc[0][tl], 0, 0, 0);
        acc[1][tl] = __builtin_amdgcn_mfma_f32_16x16x32_bf16(a4[1][c], b, acc[1][tl], 0, 0, 0);
      }
    }
#pragma unroll
    for (int tl = 0; tl < 4; ++tl) {
      int tg = hf * 4 + tl;
      float bv = bfv[tg * 16 + m];
#pragma unroll
      for (int tt = 0; tt < 2; ++tt) {
#pragma unroll
        for (int r = 0; r < 4; ++r) {
          float fpv = fmaxf(acc[tt][tl][r] + bv, 0.f);
          float fav = bf2f(buf[tt][(q * 4 + r) * 136 + tg * 16 + m]);
          float d = fpv - fav;
          pe[tt][r] += d * d;
        }
      }
    }
  }

  // reduce pe / ||fa||^2 across the 16 lanes of each quad
#pragma unroll
  for (int tt = 0; tt < 2; ++tt)
#pragma unroll
    for (int r = 0; r < 4; ++r)
#pragma unroll
      for (int msk = 1; msk < 16; msk <<= 1) {
        pe[tt][r] += __shfl_xor(pe[tt][r], msk, 16);
        a2s[tt][r] += __shfl_xor(a2s[tt][r], msk, 16);
      }

  // ---- GEMM5: g = fa @ seen^T (N=112 incl pad), d2 = a2 + s2 - 2g
  v8s a5[2][4];
#pragma unroll
  for (int tt = 0; tt < 2; ++tt)
#pragma unroll
    for (int c = 0; c < 4; ++c) a5[tt][c] = read_frag(buf[tt], m, q, c);
  float dmin[2][4] = {{3.4e38f, 3.4e38f, 3.4e38f, 3.4e38f},
                      {3.4e38f, 3.4e38f, 3.4e38f, 3.4e38f}};
#pragma unroll
  for (int tl = 0; tl < 7; ++tl) {
    v4f g0 = {}, g1 = {};
#pragma unroll
    for (int c = 0; c < 4; ++c) {
      v8s b = wfrag(wsb, WS_SEEN, tl * 4 + c, lane);
      g0 = __builtin_amdgcn_mfma_f32_16x16x32_bf16(a5[0][c], b, g0, 0, 0, 0);
      g1 = __builtin_amdgcn_mfma_f32_16x16x32_bf16(a5[1][c], b, g1, 0, 0, 0);
    }
    float s2v = s2g[tl * 16 + m];
#pragma unroll
    for (int r = 0; r < 4; ++r) {
      dmin[0][r] = fminf(dmin[0][r], a2s[0][r] + s2v - 2.f * g0[r]);
      dmin[1][r] = fminf(dmin[1][r], a2s[1][r] + s2v - 2.f * g1[r]);
    }
  }
#pragma unroll
  for (int tt = 0; tt < 2; ++tt)
#pragma unroll
    for (int r = 0; r < 4; ++r)
#pragma unroll
      for (int msk = 1; msk < 16; msk <<= 1)
        dmin[tt][r] = fminf(dmin[tt][r], __shfl_xor(dmin[tt][r], msk, 16));

  if (m == 0) {
#pragma unroll
    for (int tt = 0; tt < 2; ++tt)
#pragma unroll
      for (int r = 0; r < 4; ++r) {
        int rl = w * 32 + tt * 16 + q * 4 + r;
        float p = pe[tt][r] * (1.f / 128.f);
        float nov = fminf(1.f, sqrtf(fmaxf(dmin[tt][r], 0.f)) * 0.1f);
        s_o[0][rl] = p;
        s_o[1][rl] = nov;
        s_o[2][rl] = 0.5f * (p + nov);
      }
  }
  __syncthreads();
  const size_t base = (size_t)blockIdx.x * 128;
  for (int idx = tid; idx < 384; idx += 256) {
    int j = idx >> 7, r = idx & 127;
    out[(size_t)j * B_TOT + base + r] = s_o[j][r];
  }
}

extern "C" void kernel_launch(void* const* d_in, const int* in_sizes, int n_in,
                              void* d_out, int out_size, void* d_ws, size_t ws_size,
                              hipStream_t stream) {
  const float* state      = (const float*)d_in[0];
  const float* action     = (const float*)d_in[1];
  const float* next_state = (const float*)d_in[2];
  const float* seen       = (const float*)d_in[3];
  const float* W1         = (const float*)d_in[4];
  const float* b1         = (const float*)d_in[5];
  const float* W2         = (const float*)d_in[6];
  const float* b2         = (const float*)d_in[7];
  const float* Wf         = (const float*)d_in[8];
  const float* bf_        = (const float*)d_in[9];

  unsigned short* wsb = (unsigned short*)d_ws;
  float* s2 = (float*)((char*)d_ws + WS_S2_BYTES);

  curiosity_prep<<<292, 256, 0, stream>>>(W1, W2, Wf, seen, wsb, s2);
  curiosity_main<<<2048, 256, 0, stream>>>(state, action, next_state, b1, b2, bf_,
                                           wsb, s2, (float*)d_out);
}

// Round 3
// 376.054 us; speedup vs baseline: 1.0767x; 1.0248x over previous
//
#include <hip/hip_runtime.h>
#include <hip/hip_bf16.h>
#include <math.h>

#define B_TOT 262144

typedef __attribute__((ext_vector_type(8))) short v8s;
typedef __attribute__((ext_vector_type(4))) float v4f;

// ws layout (bf16 element offsets):
//  W1 frag-order   [0, 20480)        (8 n-tiles x 5 k-chunks x 512)
//  W2 frag-order   [20480, 36864)    (8 x 4 x 512)
//  Wf frag-order   [36864, 53248)    (8 x 4 x 512)
//  seen frag-order [53248, 67584)    (7 x 4 x 512, rows >=100 zero-padded)
//  s2 (fp32)       byte offset 135168, 112 floats (1e30 for pad rows)
#define WS_W1 0
#define WS_W2 20480
#define WS_WF 36864
#define WS_SEEN 53248
#define WS_S2_BYTES 135168

__device__ __forceinline__ unsigned short f2bf(float f) {
  union { float f; unsigned u; } cv; cv.f = f;
  unsigned u = cv.u;
  return (unsigned short)((u + 0x7FFFu + ((u >> 16) & 1u)) >> 16);  // RNE
}
__device__ __forceinline__ float bf2f(unsigned short h) {
  union { unsigned u; float f; } cv; cv.u = ((unsigned)h) << 16;
  return cv.f;
}
// packed RNE f32x2 -> bf16x2 (v_cvt_pk_bf16_f32 on gfx950); low 16 = x
__device__ __forceinline__ unsigned f2bf2(float x, float y) {
  float2 f; f.x = x; f.y = y;
  __hip_bfloat162 h = __float22bfloat162_rn(f);
  union { __hip_bfloat162 h; unsigned u; } cv; cv.h = h;
  return cv.u;
}

// Repack weights to bf16 in MFMA B-fragment-linear order.
// B-frag for (tile t, k-chunk c): lane L holds B[n = t*16 + (L&15)][k = c*32 + (L>>4)*8 + j]
__global__ void curiosity_prep(const float* __restrict__ W1, const float* __restrict__ W2,
                               const float* __restrict__ Wf, const float* __restrict__ seen,
                               unsigned short* __restrict__ wsb, float* __restrict__ s2) {
  int bid = blockIdx.x;
  if (bid < 264) {
    int idx = bid * 256 + (int)threadIdx.x;  // < 67584
    if (idx < 20480) {                       // W1: [128][160]
      int f = idx >> 9, r = idx & 511, L = r >> 3, j = r & 7;
      int t = f / 5, c = f - t * 5;
      int n = t * 16 + (L & 15), k = c * 32 + (L >> 4) * 8 + j;
      wsb[idx] = f2bf(W1[n * 160 + k]);
    } else if (idx < 36864) {                // W2: [128][128]
      int e = idx - 20480;
      int f = e >> 9, r = e & 511, L = r >> 3, j = r & 7;
      int t = f >> 2, c = f & 3;
      int n = t * 16 + (L & 15), k = c * 32 + (L >> 4) * 8 + j;
      wsb[idx] = f2bf(W2[n * 128 + k]);
    } else if (idx < 53248) {                // Wf: [128][128]
      int e = idx - 36864;
      int f = e >> 9, r = e & 511, L = r >> 3, j = r & 7;
      int t = f >> 2, c = f & 3;
      int n = t * 16 + (L & 15), k = c * 32 + (L >> 4) * 8 + j;
      wsb[idx] = f2bf(Wf[n * 128 + k]);
    } else {                                 // seen: [100->112][128]
      int e = idx - 53248;
      int f = e >> 9, r = e & 511, L = r >> 3, j = r & 7;
      int t = f >> 2, c = f & 3;
      int n = t * 16 + (L & 15), k = c * 32 + (L >> 4) * 8 + j;
      float v = (n < 100) ? seen[n * 128 + k] : 0.f;
      wsb[idx] = f2bf(v);
    }
  } else {                                   // s2: one wave per row
    int wv = (int)threadIdx.x >> 6, lane = (int)threadIdx.x & 63;
    int mm = (bid - 264) * 4 + wv;           // 0..111
    float s;
    if (mm < 100) {
      float v0 = seen[mm * 128 + lane], v1 = seen[mm * 128 + 64 + lane];
      s = v0 * v0 + v1 * v1;
#pragma unroll
      for (int msk = 1; msk < 64; msk <<= 1) s += __shfl_xor(s, msk, 64);
    } else {
      s = 1e30f;
    }
    if (lane == 0) s2[mm] = s;
  }
}

// stage a [16 x 128] f32 tile into wave-private LDS as bf16, row stride 136.
// Loads batched first (8 float4 in flight), then packed-converted + stored.
__device__ __forceinline__ void stage16x128(const float* __restrict__ src,
                                            unsigned short* buf, int lane) {
  float4 v[8];
#pragma unroll
  for (int i = 0; i < 8; ++i) {
    int flat = i * 64 + lane;
    v[i] = *(const float4*)(src + (flat >> 5) * 128 + (flat & 31) * 4);
  }
#pragma unroll
  for (int i = 0; i < 8; ++i) {
    int flat = i * 64 + lane;
    uint2 p;
    p.x = f2bf2(v[i].x, v[i].y);
    p.y = f2bf2(v[i].z, v[i].w);
    *(uint2*)(buf + (flat >> 5) * 136 + (flat & 31) * 4) = p;
  }
}
// stage a [16 x 32] f32 tile into cols 0..31 of the buffer
__device__ __forceinline__ void stage16x32(const float* __restrict__ src,
                                           unsigned short* buf, int lane) {
  float4 v[2];
#pragma unroll
  for (int i = 0; i < 2; ++i) {
    int flat = i * 64 + lane;
    v[i] = *(const float4*)(src + (flat >> 3) * 32 + (flat & 7) * 4);
  }
#pragma unroll
  for (int i = 0; i < 2; ++i) {
    int flat = i * 64 + lane;
    uint2 p;
    p.x = f2bf2(v[i].x, v[i].y);
    p.y = f2bf2(v[i].z, v[i].w);
    *(uint2*)(buf + (flat >> 3) * 136 + (flat & 7) * 4) = p;
  }
}
__device__ __forceinline__ v8s read_frag(const unsigned short* buf, int m, int q, int c) {
  return *(const v8s*)(buf + m * 136 + c * 32 + q * 8);
}
__device__ __forceinline__ v8s wfrag(const unsigned short* __restrict__ wsb,
                                     int base, int fragIdx, int lane) {
  return *(const v8s*)(wsb + base + fragIdx * 512 + lane * 8);
}

// 2048 blocks x 256 threads; 4 waves/block; each wave owns 32 rows (2 row-tiles
// sharing every B-fragment). B-frags batched into registers per phase for MLP.
// LDS = 4 x 2 x 4.25KB + 1.5KB = 36.4KB. launch_bounds(256,3): ~168 VGPR budget.
__global__ __launch_bounds__(256, 3) void curiosity_main(
    const float* __restrict__ state, const float* __restrict__ action,
    const float* __restrict__ next_state,
    const float* __restrict__ b1, const float* __restrict__ b2,
    const float* __restrict__ bfv,
    const unsigned short* __restrict__ wsb, const float* __restrict__ s2g,
    float* __restrict__ out) {
  __shared__ __attribute__((aligned(16))) unsigned short s_int[4][2][2176];
  __shared__ float s_o[3][128];

  const int tid = (int)threadIdx.x;
  const int w = tid >> 6, lane = tid & 63;
  const int m = lane & 15, q = lane >> 4;
  const int rowblk = (int)blockIdx.x * 128 + w * 32;

  unsigned short* buf[2] = { &s_int[w][0][0], &s_int[w][1][0] };

  // bias b1 preload (off critical path)
  float bv1[8];
#pragma unroll
  for (int tg = 0; tg < 8; ++tg) bv1[tg] = b1[tg * 16 + m];

  // ---- stage inputs for GEMM1: action frags first, then state over same cols
  v8s a1[2][5];
  stage16x32(action + (size_t)(rowblk) * 32, buf[0], lane);
  stage16x32(action + (size_t)(rowblk + 16) * 32, buf[1], lane);
  a1[0][4] = *(const v8s*)(buf[0] + m * 136 + q * 8);
  a1[1][4] = *(const v8s*)(buf[1] + m * 136 + q * 8);
  stage16x128(state + (size_t)(rowblk) * 128, buf[0], lane);
  stage16x128(state + (size_t)(rowblk + 16) * 128, buf[1], lane);
#pragma unroll
  for (int c = 0; c < 4; ++c) {
    a1[0][c] = read_frag(buf[0], m, q, c);
    a1[1][c] = read_frag(buf[1], m, q, c);
  }

  float bv2[8];
#pragma unroll
  for (int tg = 0; tg < 8; ++tg) bv2[tg] = b2[tg * 16 + m];

  // ---- GEMM1: h = relu(x @ W1^T + b1)
#pragma unroll
  for (int hf = 0; hf < 2; ++hf) {
    v8s bfr[20];
#pragma unroll
    for (int c = 0; c < 5; ++c)
#pragma unroll
      for (int tl = 0; tl < 4; ++tl)
        bfr[c * 4 + tl] = wfrag(wsb, WS_W1, (hf * 4 + tl) * 5 + c, lane);
    v4f acc[2][4] = {};
#pragma unroll
    for (int c = 0; c < 5; ++c)
#pragma unroll
      for (int tl = 0; tl < 4; ++tl) {
        acc[0][tl] = __builtin_amdgcn_mfma_f32_16x16x32_bf16(a1[0][c], bfr[c * 4 + tl], acc[0][tl], 0, 0, 0);
        acc[1][tl] = __builtin_amdgcn_mfma_f32_16x16x32_bf16(a1[1][c], bfr[c * 4 + tl], acc[1][tl], 0, 0, 0);
      }
#pragma unroll
    for (int tl = 0; tl < 4; ++tl) {
      int tg = hf * 4 + tl;
      float bv = bv1[tg];
#pragma unroll
      for (int tt = 0; tt < 2; ++tt)
#pragma unroll
        for (int r = 0; r < 4; r += 2) {
          unsigned p = f2bf2(fmaxf(acc[tt][tl][r] + bv, 0.f),
                             fmaxf(acc[tt][tl][r + 1] + bv, 0.f));
          buf[tt][(q * 4 + r) * 136 + tg * 16 + m] = (unsigned short)p;
          buf[tt][(q * 4 + r + 1) * 136 + tg * 16 + m] = (unsigned short)(p >> 16);
        }
    }
  }

  // ---- GEMM2: pn = h @ W2^T + b2
  v8s af[2][4];
#pragma unroll
  for (int c = 0; c < 4; ++c) {
    af[0][c] = read_frag(buf[0], m, q, c);
    af[1][c] = read_frag(buf[1], m, q, c);
  }
  float bvf[8];
#pragma unroll
  for (int tg = 0; tg < 8; ++tg) bvf[tg] = bfv[tg * 16 + m];

#pragma unroll
  for (int hf = 0; hf < 2; ++hf) {
    v8s bfr[16];
#pragma unroll
    for (int c = 0; c < 4; ++c)
#pragma unroll
      for (int tl = 0; tl < 4; ++tl)
        bfr[c * 4 + tl] = wfrag(wsb, WS_W2, (hf * 4 + tl) * 4 + c, lane);
    v4f acc[2][4] = {};
#pragma unroll
    for (int c = 0; c < 4; ++c)
#pragma unroll
      for (int tl = 0; tl < 4; ++tl) {
        acc[0][tl] = __builtin_amdgcn_mfma_f32_16x16x32_bf16(af[0][c], bfr[c * 4 + tl], acc[0][tl], 0, 0, 0);
        acc[1][tl] = __builtin_amdgcn_mfma_f32_16x16x32_bf16(af[1][c], bfr[c * 4 + tl], acc[1][tl], 0, 0, 0);
      }
#pragma unroll
    for (int tl = 0; tl < 4; ++tl) {
      int tg = hf * 4 + tl;
      float bv = bv2[tg];
#pragma unroll
      for (int tt = 0; tt < 2; ++tt)
#pragma unroll
        for (int r = 0; r < 4; r += 2) {
          unsigned p = f2bf2(acc[tt][tl][r] + bv, acc[tt][tl][r + 1] + bv);
          buf[tt][(q * 4 + r) * 136 + tg * 16 + m] = (unsigned short)p;
          buf[tt][(q * 4 + r + 1) * 136 + tg * 16 + m] = (unsigned short)(p >> 16);
        }
    }
  }

  // ---- read pn as A-frags, then stage next_state over the same buffers
  v8s a4[2][4], a3[2][4];
#pragma unroll
  for (int c = 0; c < 4; ++c) {
    a4[0][c] = read_frag(buf[0], m, q, c);
    a4[1][c] = read_frag(buf[1], m, q, c);
  }
  stage16x128(next_state + (size_t)(rowblk) * 128, buf[0], lane);
  stage16x128(next_state + (size_t)(rowblk + 16) * 128, buf[1], lane);
#pragma unroll
  for (int c = 0; c < 4; ++c) {
    a3[0][c] = read_frag(buf[0], m, q, c);
    a3[1][c] = read_frag(buf[1], m, q, c);
  }

  float s2v[7];
#pragma unroll
  for (int tl = 0; tl < 7; ++tl) s2v[tl] = s2g[tl * 16 + m];

  // ---- GEMM3: fa = relu(ns @ Wf^T + bf); keep fa packed in regs for GEMM4,
  //      write fa (bf16) to buf for GEMM5's A-frags, accumulate ||fa||^2
  unsigned fa_pk[2][16];  // [hf][tl*4 + tt*2 + rpair]
  float a2s[2][4] = {};
#pragma unroll
  for (int hf = 0; hf < 2; ++hf) {
    v8s bfr[16];
#pragma unroll
    for (int c = 0; c < 4; ++c)
#pragma unroll
      for (int tl = 0; tl < 4; ++tl)
        bfr[c * 4 + tl] = wfrag(wsb, WS_WF, (hf * 4 + tl) * 4 + c, lane);
    v4f acc[2][4] = {};
#pragma unroll
    for (int c = 0; c < 4; ++c)
#pragma unroll
      for (int tl = 0; tl < 4; ++tl) {
        acc[0][tl] = __builtin_amdgcn_mfma_f32_16x16x32_bf16(a3[0][c], bfr[c * 4 + tl], acc[0][tl], 0, 0, 0);
        acc[1][tl] = __builtin_amdgcn_mfma_f32_16x16x32_bf16(a3[1][c], bfr[c * 4 + tl], acc[1][tl], 0, 0, 0);
      }
#pragma unroll
    for (int tl = 0; tl < 4; ++tl) {
      int tg = hf * 4 + tl;
      float bv = bvf[tg];
#pragma unroll
      for (int tt = 0; tt < 2; ++tt)
#pragma unroll
        for (int rp = 0; rp < 2; ++rp) {
          int r = rp * 2;
          unsigned p = f2bf2(fmaxf(acc[tt][tl][r] + bv, 0.f),
                             fmaxf(acc[tt][tl][r + 1] + bv, 0.f));
          fa_pk[hf][tl * 4 + tt * 2 + rp] = p;
          buf[tt][(q * 4 + r) * 136 + tg * 16 + m] = (unsigned short)p;
          buf[tt][(q * 4 + r + 1) * 136 + tg * 16 + m] = (unsigned short)(p >> 16);
          float flo = bf2f((unsigned short)p), fhi = bf2f((unsigned short)(p >> 16));
          a2s[tt][r] += flo * flo;
          a2s[tt][r + 1] += fhi * fhi;
        }
    }
  }

  // ---- GEMM4: fp = relu(pn @ Wf^T + bf); pe += (fp - fa)^2 (fa from regs)
  float pe[2][4] = {};
#pragma unroll
  for (int hf = 0; hf < 2; ++hf) {
    v8s bfr[16];
#pragma unroll
    for (int c = 0; c < 4; ++c)
#pragma unroll
      for (int tl = 0; tl < 4; ++tl)
        bfr[c * 4 + tl] = wfrag(wsb, WS_WF, (hf * 4 + tl) * 4 + c, lane);
    v4f acc[2][4] = {};
#pragma unroll
    for (int c = 0; c < 4; ++c)
#pragma unroll
      for (int tl = 0; tl < 4; ++tl) {
        acc[0][tl] = __builtin_amdgcn_mfma_f32_16x16x32_bf16(a4[0][c], bfr[c * 4 + tl], acc[0][tl], 0, 0, 0);
        acc[1][tl] = __builtin_amdgcn_mfma_f32_16x16x32_bf16(a4[1][c], bfr[c * 4 + tl], acc[1][tl], 0, 0, 0);
      }
#pragma unroll
    for (int tl = 0; tl < 4; ++tl) {
      int tg = hf * 4 + tl;
      float bv = bvf[tg];
#pragma unroll
      for (int tt = 0; tt < 2; ++tt)
#pragma unroll
        for (int rp = 0; rp < 2; ++rp) {
          int r = rp * 2;
          unsigned p = fa_pk[hf][tl * 4 + tt * 2 + rp];
          float d0 = fmaxf(acc[tt][tl][r] + bv, 0.f) - bf2f((unsigned short)p);
          float d1 = fmaxf(acc[tt][tl][r + 1] + bv, 0.f) - bf2f((unsigned short)(p >> 16));
          pe[tt][r] += d0 * d0;
          pe[tt][r + 1] += d1 * d1;
        }
    }
  }

  // reduce pe / ||fa||^2 across the 16 lanes of each quad
#pragma unroll
  for (int tt = 0; tt < 2; ++tt)
#pragma unroll
    for (int r = 0; r < 4; ++r)
#pragma unroll
      for (int msk = 1; msk < 16; msk <<= 1) {
        pe[tt][r] += __shfl_xor(pe[tt][r], msk, 16);
        a2s[tt][r] += __shfl_xor(a2s[tt][r], msk, 16);
      }

  // ---- GEMM5: g = fa @ seen^T (N=112 incl pad), d2 = a2 + s2 - 2g
  v8s a5[2][4];
#pragma unroll
  for (int c = 0; c < 4; ++c) {
    a5[0][c] = read_frag(buf[0], m, q, c);
    a5[1][c] = read_frag(buf[1], m, q, c);
  }
  float dmin[2][4] = {{3.4e38f, 3.4e38f, 3.4e38f, 3.4e38f},
                      {3.4e38f, 3.4e38f, 3.4e38f, 3.4e38f}};
  {
    v8s bfr[16];
#pragma unroll
    for (int tl = 0; tl < 4; ++tl)
#pragma unroll
      for (int c = 0; c < 4; ++c)
        bfr[tl * 4 + c] = wfrag(wsb, WS_SEEN, tl * 4 + c, lane);
#pragma unroll
    for (int tl = 0; tl < 4; ++tl) {
      v4f g0 = {}, g1 = {};
#pragma unroll
      for (int c = 0; c < 4; ++c) {
        g0 = __builtin_amdgcn_mfma_f32_16x16x32_bf16(a5[0][c], bfr[tl * 4 + c], g0, 0, 0, 0);
        g1 = __builtin_amdgcn_mfma_f32_16x16x32_bf16(a5[1][c], bfr[tl * 4 + c], g1, 0, 0, 0);
      }
      float s2x = s2v[tl];
#pragma unroll
      for (int r = 0; r < 4; ++r) {
        dmin[0][r] = fminf(dmin[0][r], a2s[0][r] + s2x - 2.f * g0[r]);
        dmin[1][r] = fminf(dmin[1][r], a2s[1][r] + s2x - 2.f * g1[r]);
      }
    }
  }
  {
    v8s bfr[12];
#pragma unroll
    for (int tl = 0; tl < 3; ++tl)
#pragma unroll
      for (int c = 0; c < 4; ++c)
        bfr[tl * 4 + c] = wfrag(wsb, WS_SEEN, (tl + 4) * 4 + c, lane);
#pragma unroll
    for (int tl = 0; tl < 3; ++tl) {
      v4f g0 = {}, g1 = {};
#pragma unroll
      for (int c = 0; c < 4; ++c) {
        g0 = __builtin_amdgcn_mfma_f32_16x16x32_bf16(a5[0][c], bfr[tl * 4 + c], g0, 0, 0, 0);
        g1 = __builtin_amdgcn_mfma_f32_16x16x32_bf16(a5[1][c], bfr[tl * 4 + c], g1, 0, 0, 0);
      }
      float s2x = s2v[tl + 4];
#pragma unroll
      for (int r = 0; r < 4; ++r) {
        dmin[0][r] = fminf(dmin[0][r], a2s[0][r] + s2x - 2.f * g0[r]);
        dmin[1][r] = fminf(dmin[1][r], a2s[1][r] + s2x - 2.f * g1[r]);
      }
    }
  }
#pragma unroll
  for (int tt = 0; tt < 2; ++tt)
#pragma unroll
    for (int r = 0; r < 4; ++r)
#pragma unroll
      for (int msk = 1; msk < 16; msk <<= 1)
        dmin[tt][r] = fminf(dmin[tt][r], __shfl_xor(dmin[tt][r], msk, 16));

  if (m == 0) {
#pragma unroll
    for (int tt = 0; tt < 2; ++tt)
#pragma unroll
      for (int r = 0; r < 4; ++r) {
        int rl = w * 32 + tt * 16 + q * 4 + r;
        float p = pe[tt][r] * (1.f / 128.f);
        float nov = fminf(1.f, sqrtf(fmaxf(dmin[tt][r], 0.f)) * 0.1f);
        s_o[0][rl] = p;
        s_o[1][rl] = nov;
        s_o[2][rl] = 0.5f * (p + nov);
      }
  }
  __syncthreads();
  const size_t base = (size_t)blockIdx.x * 128;
  for (int idx = tid; idx < 384; idx += 256) {
    int j = idx >> 7, r = idx & 127;
    out[(size_t)j * B_TOT + base + r] = s_o[j][r];
  }
}

extern "C" void kernel_launch(void* const* d_in, const int* in_sizes, int n_in,
                              void* d_out, int out_size, void* d_ws, size_t ws_size,
                              hipStream_t stream) {
  const float* state      = (const float*)d_in[0];
  const float* action     = (const float*)d_in[1];
  const float* next_state = (const float*)d_in[2];
  const float* seen       = (const float*)d_in[3];
  const float* W1         = (const float*)d_in[4];
  const float* b1         = (const float*)d_in[5];
  const float* W2         = (const float*)d_in[6];
  const float* b2         = (const float*)d_in[7];
  const float* Wf         = (const float*)d_in[8];
  const float* bf_        = (const float*)d_in[9];

  unsigned short* wsb = (unsigned short*)d_ws;
  float* s2 = (float*)((char*)d_ws + WS_S2_BYTES);

  curiosity_prep<<<292, 256, 0, stream>>>(W1, W2, Wf, seen, wsb, s2);
  curiosity_main<<<2048, 256, 0, stream>>>(state, action, next_state, b1, b2, bf_,
                                           wsb, s2, (float*)d_out);
}